// Round 5
// baseline (201.254 us; speedup 1.0000x reference)
//
#include <hip/hip_runtime.h>
#include <cstdint>
#include <cstddef>

// ---------------------------------------------------------------------------
// MHA block: out = proj( causal_softmax( (xWq)(xWk)^T / 8 ) (xWv) )
// B=4, T=2048, C=1024, H=16, D=64.  All GEMM-shaped compute on bf16 MFMA.
// ---------------------------------------------------------------------------

typedef short bf16x8 __attribute__((ext_vector_type(8)));
typedef float f32x4 __attribute__((ext_vector_type(4)));

#define MFMA32(a, b, c) __builtin_amdgcn_mfma_f32_16x16x32_bf16((a), (b), (c), 0, 0, 0)

__device__ __forceinline__ unsigned short f2b(float f) {
  unsigned int x = __builtin_bit_cast(unsigned int, f);
  x += 0x7fffu + ((x >> 16) & 1u);
  return (unsigned short)(x >> 16);
}

__device__ __forceinline__ unsigned int pack2(float a, float b) {
  return (unsigned int)f2b(a) | ((unsigned int)f2b(b) << 16);
}

__device__ __forceinline__ unsigned int cvtpk(float a, float b) {
  unsigned int r;
  asm("v_cvt_pk_bf16_f32 %0, %1, %2" : "=v"(r) : "v"(a), "v"(b));
  return r;
}

__device__ __forceinline__ float exp2v(float x) {
  float r;
  asm("v_exp_f32 %0, %1" : "=v"(r) : "v"(x));
  return r;
}

__device__ __forceinline__ void gload16(const void* g, void* l) {
  __builtin_amdgcn_global_load_lds(
      (const __attribute__((address_space(1))) void*)g,
      (__attribute__((address_space(3))) void*)l, 16, 0, 0);
}

// ---------------------------------------------------------------------------
__global__ __launch_bounds__(256) void k_conv_x(const float* __restrict__ in,
                                                unsigned short* __restrict__ out, int n4) {
  int i = blockIdx.x * 256 + threadIdx.x;
  if (i >= n4) return;
  float4 v = reinterpret_cast<const float4*>(in)[i];
  ushort4 o;
  o.x = f2b(v.x); o.y = f2b(v.y); o.z = f2b(v.z); o.w = f2b(v.w);
  reinterpret_cast<ushort4*>(out)[i] = o;
}

// ---------------------------------------------------------------------------
__global__ __launch_bounds__(256) void k_transpose(const float* __restrict__ in,
                                                   unsigned short* __restrict__ out,
                                                   int R, int C) {
  __shared__ float tile[32][33];
  int c0 = blockIdx.x * 32, r0 = blockIdx.y * 32;
  int tx = threadIdx.x & 31, ty = threadIdx.x >> 5;
#pragma unroll
  for (int j = 0; j < 4; ++j)
    tile[ty + 8 * j][tx] = in[(size_t)(r0 + ty + 8 * j) * C + c0 + tx];
  __syncthreads();
#pragma unroll
  for (int j = 0; j < 4; ++j)
    out[(size_t)(c0 + ty + 8 * j) * R + r0 + tx] = f2b(tile[tx][ty + 8 * j]);
}

// ---------------------------------------------------------------------------
// Pipelined bf16 GEMM: A (M x 1024) row-major, Bt (N x 1024) row-major, K=1024.
// BM=128, BN=256, BK=64. 512 threads = 8 waves (2M x 4N), wave-tile 64x64.
// Triple-buffered LDS (144KB), staged 2 K-tiles ahead via global_load_lds,
// 2 phases per K-tile (one per K-half of 32), counted vmcnt(9) steady-state,
// raw s_barrier pairs, setprio around MFMA, XOR-swizzled LDS chunks
// (pre-swizzled global source; matching swizzle on ds_read).
// EPI=0: scatter q/k/v (q pre-scaled log2e/8; k,v swizzled; v transposed).
// EPI=1: f32 row-major out.
// ---------------------------------------------------------------------------
template <int EPI>
__global__ __launch_bounds__(512) void k_gemm(const unsigned short* __restrict__ A,
                                              const unsigned short* __restrict__ Bt,
                                              float* __restrict__ outF,
                                              unsigned short* __restrict__ q_ws,
                                              unsigned short* __restrict__ k_ws,
                                              unsigned short* __restrict__ v_ws,
                                              int M, int N) {
  constexpr int K = 1024, NKT = 16;
  // per buffer (24576 ushorts = 48KB): A-kh0 @0, A-kh1 @4096, B-kh0 @8192, B-kh1 @16384
  __shared__ unsigned short lds[3 * 24576];  // 144KB

  // XCD-chunked remap (nwg % 8 == 0 for both GEMMs)
  const int nwg = gridDim.x * gridDim.y;
  const int f = blockIdx.x + blockIdx.y * gridDim.x;
  const int cpx = nwg >> 3;
  const int idx = (f & 7) * cpx + (f >> 3);
  const int bn = idx / gridDim.y;  // column-panel major within XCD chunk
  const int bm = idx % gridDim.y;

  const int tid = threadIdx.x, w = tid >> 6, lane = tid & 63;
  const int wm = w >> 2, wn = w & 3;
  const int c = lane & 15, g = lane >> 4;

  f32x4 acc[4][4];
#pragma unroll
  for (int i = 0; i < 4; ++i)
#pragma unroll
    for (int j = 0; j < 4; ++j) acc[i][j] = (f32x4){0.f, 0.f, 0.f, 0.f};

  // staging: each wave covers rows [w*16, w*16+16) of a 128-row slice;
  // source column pre-swizzled so linear LDS + swizzled read are consistent.
  const int srow = w * 16 + (lane >> 2);
  const int scs = (((lane & 3) ^ ((lane >> 3) & 3))) * 8;
  const unsigned short* Ag = A + (size_t)(bm * 128 + srow) * K + scs;
  const unsigned short* Bg = Bt + (size_t)(bn * 256 + srow) * K + scs;

#define STAGE(kt, h, bi)                                                       \
  {                                                                            \
    const int kb = (kt) * 64 + (h) * 32;                                       \
    gload16(Ag + kb, &lds[(bi) * 24576 + (h) * 4096 + w * 512]);               \
    gload16(Bg + kb, &lds[(bi) * 24576 + 8192 + (h) * 8192 + w * 512]);        \
    gload16(Bg + (size_t)128 * K + kb,                                         \
            &lds[(bi) * 24576 + 8192 + (h) * 8192 + 4096 + w * 512]);          \
  }

  // read-side swizzled chunk offset (ushort units)
  const int rsw = (g ^ ((c >> 1) & 3)) * 8;
  const int arow = (wm * 64 + c) * 32 + rsw;  // + mf*512
  const int brow = (wn * 64 + c) * 32 + rsw;  // + nf*512

  // prologue: stage K-tiles 0,1 into buffers 0,1 (12 loads/wave)
  STAGE(0, 0, 0)
  STAGE(0, 1, 0)
  STAGE(1, 0, 1)
  STAGE(1, 1, 1)
  asm volatile("s_waitcnt vmcnt(9)" ::: "memory");  // kt0.kh0 landed
  __builtin_amdgcn_s_barrier();

  int b0 = 0;
#pragma unroll 1
  for (int kt = 0; kt < NKT; ++kt) {
    int b2 = b0 + 2;
    if (b2 >= 3) b2 -= 3;
    const unsigned short* Ab = &lds[b0 * 24576];
    const unsigned short* Bb = &lds[b0 * 24576 + 8192];
#pragma unroll
    for (int kk = 0; kk < 2; ++kk) {
      bf16x8 af[4], bfr[4];
#pragma unroll
      for (int mf = 0; mf < 4; ++mf)
        af[mf] = *(const bf16x8*)(Ab + kk * 4096 + arow + mf * 512);
#pragma unroll
      for (int nf = 0; nf < 4; ++nf)
        bfr[nf] = *(const bf16x8*)(Bb + kk * 8192 + brow + nf * 512);
      if (kt + 2 < NKT) STAGE(kt + 2, kk, b2)
      // counted vmcnt: guarantees the NEXT phase's LDS data has landed locally
      if (kt + 2 < NKT) {
        asm volatile("s_waitcnt vmcnt(9)" ::: "memory");
      } else if (kt == NKT - 2) {
        if (kk == 0) asm volatile("s_waitcnt vmcnt(6)" ::: "memory");
        else         asm volatile("s_waitcnt vmcnt(3)" ::: "memory");
      } else {
        asm volatile("s_waitcnt vmcnt(0)" ::: "memory");
      }
      __builtin_amdgcn_s_barrier();
      __builtin_amdgcn_s_setprio(1);
#pragma unroll
      for (int mf = 0; mf < 4; ++mf)
#pragma unroll
        for (int nf = 0; nf < 4; ++nf)
          acc[mf][nf] = MFMA32(af[mf], bfr[nf], acc[mf][nf]);
      __builtin_amdgcn_s_setprio(0);
      __builtin_amdgcn_s_barrier();
    }
    ++b0;
    if (b0 == 3) b0 = 0;
  }
#undef STAGE

  const int rowb = bm * 128 + wm * 64;
  const int colb = bn * 256 + wn * 64;
  if (EPI == 1) {
#pragma unroll
    for (int mf = 0; mf < 4; ++mf)
#pragma unroll
      for (int nf = 0; nf < 4; ++nf)
#pragma unroll
        for (int r = 0; r < 4; ++r) {
          int row = rowb + mf * 16 + 4 * g + r;
          int col = colb + nf * 16 + c;
          outF[(size_t)row * N + col] = acc[mf][nf][r];
        }
  } else {
    const float QSC = 0.125f * 1.4426950408889634f;
#pragma unroll
    for (int mf = 0; mf < 4; ++mf)
#pragma unroll
      for (int nf = 0; nf < 4; ++nf)
#pragma unroll
        for (int r = 0; r < 4; ++r) {
          int row = rowb + mf * 16 + 4 * g + r;  // token row in [0, 8192)
          int col = colb + nf * 16 + c;          // [0, 3072)
          int sec = col >> 10, cc = col & 1023;
          int h = cc >> 6, d = cc & 63;
          int b = row >> 11, t = row & 2047;
          float v = acc[mf][nf][r];
          if (sec == 0) {
            q_ws[((size_t)(b * 16 + h) * 2048 + t) * 64 + d] = f2b(v * QSC);
          } else if (sec == 1) {
            int dsw = ((((d >> 3) ^ (t & 7)) & 7) << 3) | (d & 7);
            k_ws[((size_t)(b * 16 + h) * 2048 + t) * 64 + dsw] = f2b(v);
          } else {
            int tsw = (t & ~63) | (((((t >> 3) & 7) ^ (d & 7)) & 7) << 3) | (t & 7);
            v_ws[((size_t)(b * 16 + h) * 64 + d) * 2048 + tsw] = f2b(v);
          }
        }
  }
}

// ---------------------------------------------------------------------------
// Flash attention, causal. 512 blocks x 512 threads (8 waves).
// Paired q-tiles (xi, 15-xi)*128 -> uniform 34 K-tile iters/block.
// KVBLK=64, double-buffered K/V in LDS, stage issued 1 tile ahead with
// counted vmcnt(2) + RAW s_barrier (no __syncthreads drain) -> real pipeline.
// Swapped QK^T; per-lane online softmax (16 vals + 2 shfl_xor); log2e folded
// into q; defer-max; cvt_pk packing; setprio around MFMA.
// ---------------------------------------------------------------------------
__global__ __launch_bounds__(512) void k_attn(const unsigned short* __restrict__ q_ws,
                                              const unsigned short* __restrict__ k_ws,
                                              const unsigned short* __restrict__ v_ws,
                                              unsigned short* __restrict__ y_ws) {
  constexpr int T = 2048;
  __shared__ unsigned short Ks[2][64 * 64];
  __shared__ unsigned short Vs[2][64 * 64];
  const int f = blockIdx.x;
  const int f2 = (f & 7) * 64 + (f >> 3);
  const int bh = f2 >> 3;
  const int xi = f2 & 7;
  const int tid = threadIdx.x, w = tid >> 6, lane = tid & 63;
  const int c = lane & 15, g = lane >> 4;
  const int cl = c & 7;
  const size_t base = (size_t)bh * T * 64;
  const unsigned short* Kb = k_ws + base;
  const unsigned short* Vb = v_ws + base;
  const unsigned short* Qb = q_ws + base;

  const int srow = w * 8 + (lane >> 3);
  const int sch = lane & 7;

#pragma unroll 1
  for (int ph = 0; ph < 2; ++ph) {
    const int q0 = (ph == 0 ? xi : 15 - xi) * 128;
    const int qrow = q0 + 16 * w + c;
    const int q_max_wave = q0 + 16 * w + 15;
    const int n_kt = (q0 >> 6) + 2;
    bf16x8 qf[2];
#pragma unroll
    for (int u = 0; u < 2; ++u)
      qf[u] = *(const bf16x8*)(Qb + (size_t)qrow * 64 + 32 * u + 8 * g);

    f32x4 yacc[4];
#pragma unroll
    for (int i = 0; i < 4; ++i) yacc[i] = (f32x4){0.f, 0.f, 0.f, 0.f};
    float m_run = -1e30f, l_part = 0.f;

    __syncthreads();  // prior phase fully done before restaging buf 0
    gload16(Kb + (size_t)srow * 64 + sch * 8, (char*)&Ks[0][0] + w * 1024);
    gload16(Vb + (size_t)srow * T + sch * 8, (char*)&Vs[0][0] + w * 1024);

#pragma unroll 1
    for (int kt = 0; kt < n_kt; ++kt) {
      const int k0 = kt * 64;
      const int cur = kt & 1;
      if (kt + 1 < n_kt) {
        const int k0n = k0 + 64;
        gload16(Kb + (size_t)(k0n + srow) * 64 + sch * 8, (char*)&Ks[cur ^ 1][0] + w * 1024);
        gload16(Vb + (size_t)srow * T + k0n + sch * 8, (char*)&Vs[cur ^ 1][0] + w * 1024);
        asm volatile("s_waitcnt vmcnt(2)" ::: "memory");
      } else {
        asm volatile("s_waitcnt vmcnt(0)" ::: "memory");
      }
      __builtin_amdgcn_s_barrier();  // raw: keep prefetch loads in flight

      if (k0 <= q_max_wave) {
        const char* KsC = (const char*)&Ks[cur][0];
        const char* VsC = (const char*)&Vs[cur][0];
        f32x4 s[4];
        __builtin_amdgcn_s_setprio(1);
#pragma unroll
        for (int tf = 0; tf < 4; ++tf) {
          bf16x8 kf0 = *(const bf16x8*)(KsC + (16 * tf + c) * 128 + (g ^ cl) * 16);
          bf16x8 kf1 = *(const bf16x8*)(KsC + (16 * tf + c) * 128 + ((4 + g) ^ cl) * 16);
          f32x4 z = (f32x4){0.f, 0.f, 0.f, 0.f};
          z = MFMA32(kf0, qf[0], z);
          s[tf] = MFMA32(kf1, qf[1], z);
        }
        __builtin_amdgcn_s_setprio(0);
        if (k0 + 63 > q0 + 16 * w) {
#pragma unroll
          for (int tf = 0; tf < 4; ++tf)
#pragma unroll
            for (int r = 0; r < 4; ++r)
              if (k0 + 16 * tf + 4 * g + r > qrow) s[tf][r] = -1e30f;
        }
        float mx0 = fmaxf(fmaxf(s[0][0], s[0][1]), fmaxf(s[0][2], s[0][3]));
        float mx1 = fmaxf(fmaxf(s[1][0], s[1][1]), fmaxf(s[1][2], s[1][3]));
        float mx2 = fmaxf(fmaxf(s[2][0], s[2][1]), fmaxf(s[2][2], s[2][3]));
        float mx3 = fmaxf(fmaxf(s[3][0], s[3][1]), fmaxf(s[3][2], s[3][3]));
        float mx = fmaxf(fmaxf(mx0, mx1), fmaxf(mx2, mx3));
        mx = fmaxf(mx, __shfl_xor(mx, 16));
        mx = fmaxf(mx, __shfl_xor(mx, 32));
        if (__any(mx > m_run + 11.5f)) {
          float m_new = fmaxf(m_run, mx);
          float corr = exp2v(m_run - m_new);
          l_part *= corr;
#pragma unroll
          for (int i = 0; i < 4; ++i) yacc[i] *= corr;
          m_run = m_new;
        }
        float p[16];
#pragma unroll
        for (int tf = 0; tf < 4; ++tf)
#pragma unroll
          for (int r = 0; r < 4; ++r) p[tf * 4 + r] = exp2v(s[tf][r] - m_run);
        float ps = ((p[0] + p[1]) + (p[2] + p[3])) + ((p[4] + p[5]) + (p[6] + p[7]));
        ps += ((p[8] + p[9]) + (p[10] + p[11])) + ((p[12] + p[13]) + (p[14] + p[15]));
        l_part += ps;

#pragma unroll
        for (int h = 0; h < 2; ++h) {
          unsigned int lo0 = cvtpk(p[8 * h + 0], p[8 * h + 1]);
          unsigned int hi0 = cvtpk(p[8 * h + 2], p[8 * h + 3]);
          unsigned int lo1 = cvtpk(p[8 * h + 4], p[8 * h + 5]);
          unsigned int hi1 = cvtpk(p[8 * h + 6], p[8 * h + 7]);
          int a2 = 2 * (g & 1);
          int srcA = 16 * a2 + c, srcB = srcA + 16;
          unsigned int Al0 = __shfl(lo0, srcA), Ah0 = __shfl(hi0, srcA);
          unsigned int Al1 = __shfl(lo1, srcA), Ah1 = __shfl(hi1, srcA);
          unsigned int Bl0 = __shfl(lo0, srcB), Bh0 = __shfl(hi0, srcB);
          unsigned int Bl1 = __shfl(lo1, srcB), Bh1 = __shfl(hi1, srcB);
          bool f1 = (g >= 2);
          union { unsigned int u[4]; bf16x8 v; } pf;
          pf.u[0] = f1 ? Al1 : Al0;
          pf.u[1] = f1 ? Ah1 : Ah0;
          pf.u[2] = f1 ? Bl1 : Bl0;
          pf.u[3] = f1 ? Bh1 : Bh0;
          __builtin_amdgcn_s_setprio(1);
#pragma unroll
          for (int df = 0; df < 4; ++df) {
            bf16x8 vf = *(const bf16x8*)(VsC + (16 * df + c) * 128 + ((h * 4 + g) ^ cl) * 16);
            yacc[df] = MFMA32(vf, pf.v, yacc[df]);
          }
          __builtin_amdgcn_s_setprio(0);
        }
      }
      __builtin_amdgcn_s_barrier();  // readers consumed before buf restage
    }

    float lt = l_part;
    lt += __shfl_xor(lt, 16);
    lt += __shfl_xor(lt, 32);
    float inv = 1.f / lt;
    const int b = bh >> 4, hh = bh & 15;
#pragma unroll
    for (int df = 0; df < 4; ++df) {
      uint2 o;
      o.x = cvtpk(yacc[df][0] * inv, yacc[df][1] * inv);
      o.y = cvtpk(yacc[df][2] * inv, yacc[df][3] * inv);
      *(uint2*)(y_ws + (size_t)(b * 2048 + qrow) * 1024 + hh * 64 + 16 * df + 4 * g) = o;
    }
  }
}

// ---------------------------------------------------------------------------
extern "C" void kernel_launch(void* const* d_in, const int* in_sizes, int n_in,
                              void* d_out, int out_size, void* d_ws, size_t ws_size,
                              hipStream_t stream) {
  const float* x = (const float*)d_in[0];      // (4, 2048, 1024)
  const float* Wqkv = (const float*)d_in[1];   // (1024, 3072)
  const float* Wproj = (const float*)d_in[2];  // (1024, 1024)
  float* out = (float*)d_out;                  // (4, 2048, 1024)
  char* ws = (char*)d_ws;

  unsigned short* x_bf = (unsigned short*)(ws);                    // 16 MiB
  unsigned short* wqkvT = (unsigned short*)(ws + 16777216);        // 6 MiB
  unsigned short* wprojT = (unsigned short*)(ws + 23068672);       // 2 MiB
  unsigned short* q_ws = (unsigned short*)(ws + 25165824);         // 16 MiB
  unsigned short* k_ws = (unsigned short*)(ws + 41943040);         // 16 MiB
  unsigned short* v_ws = (unsigned short*)(ws + 58720256);         // 16 MiB
  unsigned short* y_ws = (unsigned short*)(ws + 75497472);         // 16 MiB

  k_conv_x<<<8192, 256, 0, stream>>>(x, x_bf, 2097152);
  k_transpose<<<dim3(96, 32), 256, 0, stream>>>(Wqkv, wqkvT, 1024, 3072);
  k_transpose<<<dim3(32, 32), 256, 0, stream>>>(Wproj, wprojT, 1024, 1024);
  k_gemm<0><<<dim3(12, 64), 512, 0, stream>>>(x_bf, wqkvT, nullptr, q_ws, k_ws, v_ws, 8192, 3072);
  k_attn<<<512, 512, 0, stream>>>(q_ws, k_ws, v_ws, y_ws);
  k_gemm<1><<<dim3(4, 64), 512, 0, stream>>>(y_ws, wprojT, out, nullptr, nullptr, nullptr, 8192, 1024);
}

// Round 6
// 196.577 us; speedup vs baseline: 1.0238x; 1.0238x over previous
//
#include <hip/hip_runtime.h>
#include <cstdint>
#include <cstddef>

// ---------------------------------------------------------------------------
// MHA block: out = proj( causal_softmax( (xWq)(xWk)^T / 8 ) (xWv) )
// B=4, T=2048, C=1024, H=16, D=64.  All GEMM-shaped compute on bf16 MFMA.
// ---------------------------------------------------------------------------

typedef short bf16x8 __attribute__((ext_vector_type(8)));
typedef float f32x4 __attribute__((ext_vector_type(4)));

#define MFMA32(a, b, c) __builtin_amdgcn_mfma_f32_16x16x32_bf16((a), (b), (c), 0, 0, 0)

__device__ __forceinline__ unsigned short f2b(float f) {
  unsigned int x = __builtin_bit_cast(unsigned int, f);
  x += 0x7fffu + ((x >> 16) & 1u);
  return (unsigned short)(x >> 16);
}

__device__ __forceinline__ unsigned int pack2(float a, float b) {
  return (unsigned int)f2b(a) | ((unsigned int)f2b(b) << 16);
}

__device__ __forceinline__ unsigned int cvtpk(float a, float b) {
  unsigned int r;
  asm("v_cvt_pk_bf16_f32 %0, %1, %2" : "=v"(r) : "v"(a), "v"(b));
  return r;
}

__device__ __forceinline__ float exp2v(float x) {
  float r;
  asm("v_exp_f32 %0, %1" : "=v"(r) : "v"(x));
  return r;
}

__device__ __forceinline__ void gload16(const void* g, void* l) {
  __builtin_amdgcn_global_load_lds(
      (const __attribute__((address_space(1))) void*)g,
      (__attribute__((address_space(3))) void*)l, 16, 0, 0);
}

// ---------------------------------------------------------------------------
__global__ __launch_bounds__(256) void k_conv_x(const float* __restrict__ in,
                                                unsigned short* __restrict__ out, int n4) {
  int i = blockIdx.x * 256 + threadIdx.x;
  if (i >= n4) return;
  float4 v = reinterpret_cast<const float4*>(in)[i];
  ushort4 o;
  o.x = f2b(v.x); o.y = f2b(v.y); o.z = f2b(v.z); o.w = f2b(v.w);
  reinterpret_cast<ushort4*>(out)[i] = o;
}

// ---------------------------------------------------------------------------
__global__ __launch_bounds__(256) void k_transpose(const float* __restrict__ in,
                                                   unsigned short* __restrict__ out,
                                                   int R, int C) {
  __shared__ float tile[32][33];
  int c0 = blockIdx.x * 32, r0 = blockIdx.y * 32;
  int tx = threadIdx.x & 31, ty = threadIdx.x >> 5;
#pragma unroll
  for (int j = 0; j < 4; ++j)
    tile[ty + 8 * j][tx] = in[(size_t)(r0 + ty + 8 * j) * C + c0 + tx];
  __syncthreads();
#pragma unroll
  for (int j = 0; j < 4; ++j)
    out[(size_t)(c0 + ty + 8 * j) * R + r0 + tx] = f2b(tile[tx][ty + 8 * j]);
}

// ---------------------------------------------------------------------------
// 8-phase 256x256 bf16 GEMM (m201 template). A (Mx1024) rm, Bt (Nx1024) rm.
// BK=64, 512 thr = 8 waves (2M x 4N), wave tile 128x64, acc[8][4].
// LDS ring: 8 slots x 16KB: slot = (t&1)*4 + {A:0,B:2} + half. Per phase:
// {ds_read 4-12 b128; stage 1 half-tile (2 gload16); barrier; lgkmcnt(0);
//  setprio(1); 16 MFMA; setprio(0); [vmcnt(4) @ p3/p7]; barrier}.
// Stage schedule per iter (compute t0 @ p0-3, t1 @ p4-7):
//   p0:A[t1]h0 p1:A[t1]h1 p2:B[t0+2]h0 p3:B[t0+2]h1
//   p4:A[t0+2]h0 p5:A[t0+2]h1 p6:B[t1+2]h0 p7:B[t1+2]h1
// (every stage >=1 barrier after its slot's last reader; every half confirmed
//  by a vmcnt+barrier before first read; tail it=7: p3 uses vmcnt(0)).
// XOR-swizzle chunk^(row&7), pre-swizzled global source -> 2-way (free).
// ---------------------------------------------------------------------------
template <int EPI>
__global__ __launch_bounds__(512) void k_gemm(const unsigned short* __restrict__ A,
                                              const unsigned short* __restrict__ Bt,
                                              float* __restrict__ outF,
                                              unsigned short* __restrict__ q_ws,
                                              unsigned short* __restrict__ k_ws,
                                              unsigned short* __restrict__ v_ws,
                                              int M, int N) {
  constexpr int K = 1024;
  __shared__ unsigned short lds[65536];  // 128KB = 8 slots x 8192 ushorts

  const int nbn = gridDim.x;
  const int nwg = gridDim.x * gridDim.y;
  const int f = blockIdx.x + blockIdx.y * gridDim.x;
  const int cpx = nwg >> 3;
  const int idx = (f & 7) * cpx + (f >> 3);
  const int bm = idx / nbn, bn = idx % nbn;

  const int tid = threadIdx.x, w = tid >> 6, lane = tid & 63;
  const int wm = w >> 2, wn = w & 3;
  const int c = lane & 15, g = lane >> 4;
  const int cl8 = c & 7;
  const int ch0 = g ^ cl8, ch1 = ch0 ^ 4;  // read-side swizzled 16B-chunk idx

  const unsigned short* Ag = A + (size_t)(bm * 256) * K;
  const unsigned short* Bg = Bt + (size_t)(bn * 256) * K;
  const int r0 = w * 8 + (lane >> 3);          // staging row within 128-half
  const int sch = (lane & 7) ^ (lane >> 3);    // pre-swizzled source chunk

  f32x4 acc[8][4];
#pragma unroll
  for (int i = 0; i < 8; ++i)
#pragma unroll
    for (int j = 0; j < 4; ++j) acc[i][j] = (f32x4){0.f, 0.f, 0.f, 0.f};

  bf16x8 af[2][2], bfr[4][2];
  const int sA0 = wm, sA1 = 4 + wm;
  const int sB0 = 2 + (wn >> 1), sB1 = 6 + (wn >> 1);

#define LDA2(sA, mf0)                                                          \
  {                                                                            \
    _Pragma("unroll") for (int mi = 0; mi < 2; ++mi) {                         \
      const int rb = (sA) * 8192 + ((mf0) + mi) * 1024 + c * 64;               \
      af[mi][0] = *(const bf16x8*)&lds[rb + ch0 * 8];                          \
      af[mi][1] = *(const bf16x8*)&lds[rb + ch1 * 8];                          \
    }                                                                          \
  }
#define LDB(sB)                                                                \
  {                                                                            \
    _Pragma("unroll") for (int nf = 0; nf < 4; ++nf) {                         \
      const int rb = (sB) * 8192 + ((wn & 1) * 64 + nf * 16 + c) * 64;         \
      bfr[nf][0] = *(const bf16x8*)&lds[rb + ch0 * 8];                         \
      bfr[nf][1] = *(const bf16x8*)&lds[rb + ch1 * 8];                         \
    }                                                                          \
  }
#define MM2(mf0)                                                               \
  {                                                                            \
    _Pragma("unroll") for (int mi = 0; mi < 2; ++mi)                           \
        _Pragma("unroll") for (int nf = 0; nf < 4; ++nf) {                     \
      acc[(mf0) + mi][nf] = MFMA32(af[mi][0], bfr[nf][0], acc[(mf0) + mi][nf]);\
      acc[(mf0) + mi][nf] = MFMA32(af[mi][1], bfr[nf][1], acc[(mf0) + mi][nf]);\
    }                                                                          \
  }
#define STG_A(t, h)                                                            \
  {                                                                            \
    gload16(Ag + (size_t)((h) * 128 + r0) * K + (t) * 64 + sch * 8,            \
            &lds[(((t) & 1) * 4 + (h)) * 8192 + w * 512]);                     \
    gload16(Ag + (size_t)((h) * 128 + 64 + r0) * K + (t) * 64 + sch * 8,       \
            &lds[(((t) & 1) * 4 + (h)) * 8192 + 4096 + w * 512]);              \
  }
#define STG_B(t, h)                                                            \
  {                                                                            \
    gload16(Bg + (size_t)((h) * 128 + r0) * K + (t) * 64 + sch * 8,            \
            &lds[(((t) & 1) * 4 + 2 + (h)) * 8192 + w * 512]);                 \
    gload16(Bg + (size_t)((h) * 128 + 64 + r0) * K + (t) * 64 + sch * 8,       \
            &lds[(((t) & 1) * 4 + 2 + (h)) * 8192 + 4096 + w * 512]);          \
  }
#define BAR                                                                    \
  __builtin_amdgcn_s_barrier();                                                \
  __builtin_amdgcn_sched_barrier(0)
#define LGKM0 asm volatile("s_waitcnt lgkmcnt(0)" ::: "memory")
#define VMC4 asm volatile("s_waitcnt vmcnt(4)" ::: "memory")
#define VMC0 asm volatile("s_waitcnt vmcnt(0)" ::: "memory")
#define PR1 __builtin_amdgcn_s_setprio(1)
#define PR0 __builtin_amdgcn_s_setprio(0)

  // prologue: A[0], B[0], B[1]; confirm A[0],B[0] landed (2 halves in flight)
  STG_A(0, 0) STG_A(0, 1) STG_B(0, 0) STG_B(0, 1) STG_B(1, 0) STG_B(1, 1)
  VMC4;
  BAR;

#pragma unroll 1
  for (int it = 0; it < 8; ++it) {
    const int t0 = 2 * it, t1 = t0 + 1;
    const bool st = (it < 7);
    // p0
    LDB(sB0) LDA2(sA0, 0) STG_A(t1, 0)
    BAR; LGKM0; PR1; MM2(0) PR0; BAR;
    // p1
    LDA2(sA0, 2) STG_A(t1, 1)
    BAR; LGKM0; PR1; MM2(2) PR0; BAR;
    // p2
    LDA2(sA0, 4) if (st) STG_B(t0 + 2, 0)
    BAR; LGKM0; PR1; MM2(4) PR0; BAR;
    // p3
    LDA2(sA0, 6) if (st) STG_B(t0 + 2, 1)
    BAR; LGKM0; PR1; MM2(6) PR0;
    if (st) { VMC4; } else { VMC0; }
    BAR;
    // p4
    LDB(sB1) LDA2(sA1, 0) if (st) STG_A(t0 + 2, 0)
    BAR; LGKM0; PR1; MM2(0) PR0; BAR;
    // p5
    LDA2(sA1, 2) if (st) STG_A(t0 + 2, 1)
    BAR; LGKM0; PR1; MM2(2) PR0; BAR;
    // p6
    LDA2(sA1, 4) if (st) STG_B(t1 + 2, 0)
    BAR; LGKM0; PR1; MM2(4) PR0; BAR;
    // p7
    LDA2(sA1, 6) if (st) STG_B(t1 + 2, 1)
    BAR; LGKM0; PR1; MM2(6) PR0;
    if (st) { VMC4; }
    BAR;
  }
#undef LDA2
#undef LDB
#undef MM2
#undef STG_A
#undef STG_B

  const int rowb = bm * 256 + wm * 128;
  const int colb = bn * 256 + wn * 64;
  if (EPI == 1) {
#pragma unroll
    for (int mf = 0; mf < 8; ++mf)
#pragma unroll
      for (int nf = 0; nf < 4; ++nf)
#pragma unroll
        for (int r = 0; r < 4; ++r) {
          int row = rowb + mf * 16 + 4 * g + r;
          int col = colb + nf * 16 + c;
          outF[(size_t)row * N + col] = acc[mf][nf][r];
        }
  } else {
    const float QSC = 0.125f * 1.4426950408889634f;
#pragma unroll
    for (int mf = 0; mf < 8; ++mf)
#pragma unroll
      for (int nf = 0; nf < 4; ++nf)
#pragma unroll
        for (int r = 0; r < 4; ++r) {
          int row = rowb + mf * 16 + 4 * g + r;  // token row in [0, 8192)
          int col = colb + nf * 16 + c;          // [0, 3072)
          int sec = col >> 10, cc = col & 1023;
          int h = cc >> 6, d = cc & 63;
          int b = row >> 11, t = row & 2047;
          float v = acc[mf][nf][r];
          if (sec == 0) {
            q_ws[((size_t)(b * 16 + h) * 2048 + t) * 64 + d] = f2b(v * QSC);
          } else if (sec == 1) {
            int dsw = ((((d >> 3) ^ (t & 7)) & 7) << 3) | (d & 7);
            k_ws[((size_t)(b * 16 + h) * 2048 + t) * 64 + dsw] = f2b(v);
          } else {
            int tsw = (t & ~63) | (((((t >> 3) & 7) ^ (d & 7)) & 7) << 3) | (t & 7);
            v_ws[((size_t)(b * 16 + h) * 64 + d) * 2048 + tsw] = f2b(v);
          }
        }
  }
}

// ---------------------------------------------------------------------------
// Flash attention, causal. 512 blocks x 512 threads (8 waves). (unchanged)
// ---------------------------------------------------------------------------
__global__ __launch_bounds__(512) void k_attn(const unsigned short* __restrict__ q_ws,
                                              const unsigned short* __restrict__ k_ws,
                                              const unsigned short* __restrict__ v_ws,
                                              unsigned short* __restrict__ y_ws) {
  constexpr int T = 2048;
  __shared__ unsigned short Ks[2][64 * 64];
  __shared__ unsigned short Vs[2][64 * 64];
  const int f = blockIdx.x;
  const int f2 = (f & 7) * 64 + (f >> 3);
  const int bh = f2 >> 3;
  const int xi = f2 & 7;
  const int tid = threadIdx.x, w = tid >> 6, lane = tid & 63;
  const int c = lane & 15, g = lane >> 4;
  const int cl = c & 7;
  const size_t base = (size_t)bh * T * 64;
  const unsigned short* Kb = k_ws + base;
  const unsigned short* Vb = v_ws + base;
  const unsigned short* Qb = q_ws + base;

  const int srow = w * 8 + (lane >> 3);
  const int sch = lane & 7;

#pragma unroll 1
  for (int ph = 0; ph < 2; ++ph) {
    const int q0 = (ph == 0 ? xi : 15 - xi) * 128;
    const int qrow = q0 + 16 * w + c;
    const int q_max_wave = q0 + 16 * w + 15;
    const int n_kt = (q0 >> 6) + 2;
    bf16x8 qf[2];
#pragma unroll
    for (int u = 0; u < 2; ++u)
      qf[u] = *(const bf16x8*)(Qb + (size_t)qrow * 64 + 32 * u + 8 * g);

    f32x4 yacc[4];
#pragma unroll
    for (int i = 0; i < 4; ++i) yacc[i] = (f32x4){0.f, 0.f, 0.f, 0.f};
    float m_run = -1e30f, l_part = 0.f;

    __syncthreads();  // prior phase fully done before restaging buf 0
    gload16(Kb + (size_t)srow * 64 + sch * 8, (char*)&Ks[0][0] + w * 1024);
    gload16(Vb + (size_t)srow * T + sch * 8, (char*)&Vs[0][0] + w * 1024);

#pragma unroll 1
    for (int kt = 0; kt < n_kt; ++kt) {
      const int k0 = kt * 64;
      const int cur = kt & 1;
      if (kt + 1 < n_kt) {
        const int k0n = k0 + 64;
        gload16(Kb + (size_t)(k0n + srow) * 64 + sch * 8, (char*)&Ks[cur ^ 1][0] + w * 1024);
        gload16(Vb + (size_t)srow * T + k0n + sch * 8, (char*)&Vs[cur ^ 1][0] + w * 1024);
        asm volatile("s_waitcnt vmcnt(2)" ::: "memory");
      } else {
        asm volatile("s_waitcnt vmcnt(0)" ::: "memory");
      }
      __builtin_amdgcn_s_barrier();

      if (k0 <= q_max_wave) {
        const char* KsC = (const char*)&Ks[cur][0];
        const char* VsC = (const char*)&Vs[cur][0];
        f32x4 s[4];
        __builtin_amdgcn_s_setprio(1);
#pragma unroll
        for (int tf = 0; tf < 4; ++tf) {
          bf16x8 kf0 = *(const bf16x8*)(KsC + (16 * tf + c) * 128 + (g ^ cl) * 16);
          bf16x8 kf1 = *(const bf16x8*)(KsC + (16 * tf + c) * 128 + ((4 + g) ^ cl) * 16);
          f32x4 z = (f32x4){0.f, 0.f, 0.f, 0.f};
          z = MFMA32(kf0, qf[0], z);
          s[tf] = MFMA32(kf1, qf[1], z);
        }
        __builtin_amdgcn_s_setprio(0);
        if (k0 + 63 > q0 + 16 * w) {
#pragma unroll
          for (int tf = 0; tf < 4; ++tf)
#pragma unroll
            for (int r = 0; r < 4; ++r)
              if (k0 + 16 * tf + 4 * g + r > qrow) s[tf][r] = -1e30f;
        }
        float mx0 = fmaxf(fmaxf(s[0][0], s[0][1]), fmaxf(s[0][2], s[0][3]));
        float mx1 = fmaxf(fmaxf(s[1][0], s[1][1]), fmaxf(s[1][2], s[1][3]));
        float mx2 = fmaxf(fmaxf(s[2][0], s[2][1]), fmaxf(s[2][2], s[2][3]));
        float mx3 = fmaxf(fmaxf(s[3][0], s[3][1]), fmaxf(s[3][2], s[3][3]));
        float mx = fmaxf(fmaxf(mx0, mx1), fmaxf(mx2, mx3));
        mx = fmaxf(mx, __shfl_xor(mx, 16));
        mx = fmaxf(mx, __shfl_xor(mx, 32));
        if (__any(mx > m_run + 11.5f)) {
          float m_new = fmaxf(m_run, mx);
          float corr = exp2v(m_run - m_new);
          l_part *= corr;
#pragma unroll
          for (int i = 0; i < 4; ++i) yacc[i] *= corr;
          m_run = m_new;
        }
        float p[16];
#pragma unroll
        for (int tf = 0; tf < 4; ++tf)
#pragma unroll
          for (int r = 0; r < 4; ++r) p[tf * 4 + r] = exp2v(s[tf][r] - m_run);
        float ps = ((p[0] + p[1]) + (p[2] + p[3])) + ((p[4] + p[5]) + (p[6] + p[7]));
        ps += ((p[8] + p[9]) + (p[10] + p[11])) + ((p[12] + p[13]) + (p[14] + p[15]));
        l_part += ps;

#pragma unroll
        for (int h = 0; h < 2; ++h) {
          unsigned int lo0 = cvtpk(p[8 * h + 0], p[8 * h + 1]);
          unsigned int hi0 = cvtpk(p[8 * h + 2], p[8 * h + 3]);
          unsigned int lo1 = cvtpk(p[8 * h + 4], p[8 * h + 5]);
          unsigned int hi1 = cvtpk(p[8 * h + 6], p[8 * h + 7]);
          int a2 = 2 * (g & 1);
          int srcA = 16 * a2 + c, srcB = srcA + 16;
          unsigned int Al0 = __shfl(lo0, srcA), Ah0 = __shfl(hi0, srcA);
          unsigned int Al1 = __shfl(lo1, srcA), Ah1 = __shfl(hi1, srcA);
          unsigned int Bl0 = __shfl(lo0, srcB), Bh0 = __shfl(hi0, srcB);
          unsigned int Bl1 = __shfl(lo1, srcB), Bh1 = __shfl(hi1, srcB);
          bool f1 = (g >= 2);
          union { unsigned int u[4]; bf16x8 v; } pf;
          pf.u[0] = f1 ? Al1 : Al0;
          pf.u[1] = f1 ? Ah1 : Ah0;
          pf.u[2] = f1 ? Bl1 : Bl0;
          pf.u[3] = f1 ? Bh1 : Bh0;
          __builtin_amdgcn_s_setprio(1);
#pragma unroll
          for (int df = 0; df < 4; ++df) {
            bf16x8 vf = *(const bf16x8*)(VsC + (16 * df + c) * 128 + ((h * 4 + g) ^ cl) * 16);
            yacc[df] = MFMA32(vf, pf.v, yacc[df]);
          }
          __builtin_amdgcn_s_setprio(0);
        }
      }
      __builtin_amdgcn_s_barrier();
    }

    float lt = l_part;
    lt += __shfl_xor(lt, 16);
    lt += __shfl_xor(lt, 32);
    float inv = 1.f / lt;
    const int b = bh >> 4, hh = bh & 15;
#pragma unroll
    for (int df = 0; df < 4; ++df) {
      uint2 o;
      o.x = cvtpk(yacc[df][0] * inv, yacc[df][1] * inv);
      o.y = cvtpk(yacc[df][2] * inv, yacc[df][3] * inv);
      *(uint2*)(y_ws + (size_t)(b * 2048 + qrow) * 1024 + hh * 64 + 16 * df + 4 * g) = o;
    }
  }
}

// ---------------------------------------------------------------------------
extern "C" void kernel_launch(void* const* d_in, const int* in_sizes, int n_in,
                              void* d_out, int out_size, void* d_ws, size_t ws_size,
                              hipStream_t stream) {
  const float* x = (const float*)d_in[0];      // (4, 2048, 1024)
  const float* Wqkv = (const float*)d_in[1];   // (1024, 3072)
  const float* Wproj = (const float*)d_in[2];  // (1024, 1024)
  float* out = (float*)d_out;                  // (4, 2048, 1024)
  char* ws = (char*)d_ws;

  unsigned short* x_bf = (unsigned short*)(ws);                    // 16 MiB
  unsigned short* wqkvT = (unsigned short*)(ws + 16777216);        // 6 MiB
  unsigned short* wprojT = (unsigned short*)(ws + 23068672);       // 2 MiB
  unsigned short* q_ws = (unsigned short*)(ws + 25165824);         // 16 MiB
  unsigned short* k_ws = (unsigned short*)(ws + 41943040);         // 16 MiB
  unsigned short* v_ws = (unsigned short*)(ws + 58720256);         // 16 MiB
  unsigned short* y_ws = (unsigned short*)(ws + 75497472);         // 16 MiB

  k_conv_x<<<8192, 256, 0, stream>>>(x, x_bf, 2097152);
  k_transpose<<<dim3(96, 32), 256, 0, stream>>>(Wqkv, wqkvT, 1024, 3072);
  k_transpose<<<dim3(32, 32), 256, 0, stream>>>(Wproj, wprojT, 1024, 1024);
  k_gemm<0><<<dim3(12, 32), 512, 0, stream>>>(x_bf, wqkvT, nullptr, q_ws, k_ws, v_ws, 8192, 3072);
  k_attn<<<512, 512, 0, stream>>>(q_ws, k_ws, v_ws, y_ws);
  k_gemm<1><<<dim3(4, 32), 512, 0, stream>>>(y_ws, wprojT, out, nullptr, nullptr, nullptr, 8192, 1024);
}